// Round 5
// baseline (186497.485 us; speedup 1.0000x reference)
//
#include <hip/hip_runtime.h>
#include <math.h>

// B=256 T=512 DIN=25 P=128 HID=256 3H=768 L=5 Q=0.15 EPS=1e-5
// Full-fp32. R9: ABANDON the cross-block h-exchange (R5-R8: 56-78ms, all
// worse than the 48ms R4 baseline -- per-step agent-scope exchange costs
// ~= the weight stream it eliminated). New recur: one block owns 8 SORTED
// samples x all 256 h-dims x one dir. Thread j owns gates {r,z,n} for
// h-dim j across the 8 samples (24 loop-carried accumulators -- NOT
// rematerializable, so the R5-R7 spill/remat failure mode cannot apply).
// Whh streams from L2 once per step serving 8 samples (768KB/step ~5.7us,
// balanced vs 6144 FMA/thread ~5.1us) = 8x less stream per sample-step
// than R4. h state in 16KB LDS ping-pong, 1 barrier/step, gate update
// thread-local, ZERO cross-block traffic. Fused with the gemm role (R4's
// proven overlap structure, recur blocks first). New Bg=256 tier halves
// the serial round count (1 sample group instead of 2) when workspace
// allows (~746MB); falls back to 128.

#define CH 64

// ---------------- stable sort + per-group chunk counts ----------------
__global__ __launch_bounds__(256)
void sort_k(const int* __restrict__ len, int* __restrict__ perm,
            int* __restrict__ nchp, int Bg)
{
    __shared__ int ll[256];
    __shared__ int lp[256];
    const int i = threadIdx.x;
    const int li = len[i];
    ll[i] = li;
    __syncthreads();
    int rk = 0;
    for (int j = 0; j < 256; j++) {
        int lj = ll[j];
        rk += (lj < li || (lj == li && j < i)) ? 1 : 0;
    }
    lp[rk] = i;
    __syncthreads();
    perm[i] = lp[i];
    const int ngrp = 256 / Bg;
    if (i < ngrp) {
        int mx = ll[lp[i * Bg + Bg - 1]];      // ascending -> last rank is max
        int nch = (mx + 63) >> 6;
        nchp[i] = nch < 1 ? 1 : (nch > 8 ? 8 : nch);
    }
}

// ---------------- Whh pack: wpk[u][k4][g3][j][k'] ----------------
// u = l*2+d. Element (u,k4,g3,j,k') = Whh_raw[u][g3*256+j][k4*4+k'].
// In recur_k, at fixed (k4,g3) lane j reads float4 at offset
// ((k4*3+g3)*256 + j)*4 -> 16B/lane, lane-consecutive = perfectly
// coalesced 1KB/instr L2 stream. Layer stride 393216 floats.
__global__ __launch_bounds__(256)
void prep_whhT_k(const float* __restrict__ Whh0, const float* __restrict__ Whh,
                 float* __restrict__ out)
{
    int id = blockIdx.x * 256 + threadIdx.x;   // exactly 1,966,080 threads
    int kp = id & 3;  int rest = id >> 2;
    int j  = rest & 255; rest >>= 8;
    int g3 = rest % 3;   rest /= 3;
    int k4 = rest & 63;  rest >>= 6;           // rest = u = l*2+d
    int l = rest >> 1, d = rest & 1;
    int row = g3 * 256 + j;
    int col = k4 * 4 + kp;
    out[id] = (l == 0) ? Whh0[(size_t)(d * 768 + row) * 256 + col]
                       : Whh[(size_t)(((l - 1) * 2 + d) * 768 + row) * 256 + col];
}

// ---------------- input projection: LN -> FC(25->128) -> GELU -> FC(128->128) --
__global__ __launch_bounds__(128)
void input_proj_k(const float* __restrict__ x, const int* __restrict__ lengths,
                  const int* __restrict__ perm,
                  const float* __restrict__ lng, const float* __restrict__ lnb,
                  const float* __restrict__ w1, const float* __restrict__ b1v,
                  const float* __restrict__ w2, const float* __restrict__ b2v,
                  float* __restrict__ out, int g0)
{
    const int btl = blockIdx.x;                // group-local (sl*512 + t)
    const int sl  = btl >> 9;
    const int t   = btl & 511;
    const int b   = perm[g0 + sl];
    if (t >= lengths[b]) return;               // masked rows never read downstream
    const int tid = threadIdx.x;
    __shared__ float xs[25];
    __shared__ float xn[25];
    __shared__ float hs[128];
    if (tid < 25) xs[tid] = x[((size_t)b * 512 + t) * 25 + tid];
    __syncthreads();
    if (tid < 25) {
        float mu = 0.f;
        #pragma unroll
        for (int k = 0; k < 25; k++) mu += xs[k];
        mu *= (1.f / 25.f);
        float var = 0.f;
        #pragma unroll
        for (int k = 0; k < 25; k++) { float dd = xs[k] - mu; var += dd * dd; }
        var *= (1.f / 25.f);
        float rstd = 1.f / sqrtf(var + 1e-5f);
        xn[tid] = (xs[tid] - mu) * rstd * lng[tid] + lnb[tid];
    }
    __syncthreads();
    float a = b1v[tid];
    #pragma unroll
    for (int k = 0; k < 25; k++) a = fmaf(xn[k], w1[k * 128 + tid], a);
    float ge = 0.5f * a * (1.f + erff(a * 0.70710678118654752440f));
    hs[tid] = ge;
    __syncthreads();
    float o = b2v[tid];
    #pragma unroll 8
    for (int k = 0; k < 128; k++) o = fmaf(hs[k], w2[k * 128 + tid], o);
    out[(size_t)btl * 128 + tid] = o;
}

// ---------------- fused round ----------------
// blocks [0, NR): recur role, NR = Bg/4. Block = (dir d, subgroup sg of 8
//   consecutive sorted samples). Thread j = gates {r,z,n} of h-dim j for
//   all 8 samples; full-K dots; weight stream 768KB/step shared by the 8
//   samples; h in LDS ping-pong; 1 barrier/step; NO cross-block traffic.
//   hstate persists per (d, sample) across rounds via plain global
//   (kernel-boundary coherence, proven in R4).
// blocks [NR, NR+12*Bg): GEMM role (unchanged). 64Mx128N tile, K via LDS.
__global__ __launch_bounds__(256)
void round_k(const float* __restrict__ A, int K,
             const float* __restrict__ W,      // raw Wih layer slice [2][768][K]
             const float* __restrict__ bi,     // [2][768]
             const int* __restrict__ lengths, const int* __restrict__ perm,
             const int* __restrict__ nchp, int gidx, int g0, int Bg,
             float* __restrict__ xw_w,         // gemm out (round r)
             const float* __restrict__ xw_r,   // recur in (round r-1)
             const float* __restrict__ whhT,   // packed layer slice (393216 f)
             const float* __restrict__ bhh,    // [2][768]
             float* __restrict__ Y,            // bout [Bg*512][512]
             float* __restrict__ hstate,       // [2][Bg][256]
             int NR, int r)
{
    __shared__ float smem[4096];               // 16KB union of both roles

    const int tid = threadIdx.x;
    const int nch = nchp[gidx];

    if ((int)blockIdx.x < NR) {
        // ================= recur role =================
        if (r == 0) return;
        const int half = NR >> 1;              // Bg/8 subgroups per dir
        const int d  = ((int)blockIdx.x >= half) ? 1 : 0;
        const int sg = (int)blockIdx.x - d * half;
        const int lo = d ? (nch - r) * CH : (r - 1) * CH;
        if (lo < 0 || lo >= 512) return;
        const int mlsg = lengths[perm[g0 + sg * 8 + 7]];   // subgroup max (sorted)
        int nst = min(lo + CH, mlsg) - lo;
        if (nst <= 0) return;
        const bool first = d ? (mlsg <= lo + CH) : (r == 1);

        float* h_cur = smem;                   // [8][256]
        float* h_nxt = smem + 2048;

        int lenv[8];
        #pragma unroll
        for (int s = 0; s < 8; s++) lenv[s] = lengths[perm[g0 + sg * 8 + s]];

        const float bh0 = bhh[d * 768 + tid];
        const float bh1 = bhh[d * 768 + 256 + tid];
        const float bh2 = bhh[d * 768 + 512 + tid];

        float* hst = hstate + (size_t)(d * Bg + sg * 8) * 256;
        if (first) {
            #pragma unroll
            for (int s = 0; s < 8; s++) h_cur[s * 256 + tid] = 0.f;
        } else {
            #pragma unroll
            for (int s = 0; s < 8; s++) h_cur[s * 256 + tid] = hst[s * 256 + tid];
        }
        __syncthreads();

        // packed weight base for (d, thread j=tid): float4 at
        // wd4[(k4*3+g3)*256] walks k4=0..63, lane-consecutive 16B.
        const float4* wd4 = (const float4*)whhT + (size_t)d * 49152 + tid;
        const float* xb = xw_r + ((size_t)(d * Bg + sg * 8) * 64) * 768 + tid;

        for (int st = 0; st < nst; st++) {
            const int p   = d ? (lo + nst - 1 - st) : (lo + st);
            const int row = p - lo;

            float a0[8], a1[8], a2[8];
            #pragma unroll
            for (int s = 0; s < 8; s++) { a0[s] = 0.f; a1[s] = 0.f; a2[s] = 0.f; }

            #pragma unroll 8
            for (int k4 = 0; k4 < 64; k4++) {
                const float4 w0v = wd4[(k4 * 3 + 0) * 256];
                const float4 w1v = wd4[(k4 * 3 + 1) * 256];
                const float4 w2v = wd4[(k4 * 3 + 2) * 256];
                #pragma unroll
                for (int s = 0; s < 8; s++) {
                    const float4 h4 = *(const float4*)&h_cur[s * 256 + k4 * 4];
                    a0[s] = fmaf(h4.x, w0v.x, a0[s]);
                    a0[s] = fmaf(h4.y, w0v.y, a0[s]);
                    a0[s] = fmaf(h4.z, w0v.z, a0[s]);
                    a0[s] = fmaf(h4.w, w0v.w, a0[s]);
                    a1[s] = fmaf(h4.x, w1v.x, a1[s]);
                    a1[s] = fmaf(h4.y, w1v.y, a1[s]);
                    a1[s] = fmaf(h4.z, w1v.z, a1[s]);
                    a1[s] = fmaf(h4.w, w1v.w, a1[s]);
                    a2[s] = fmaf(h4.x, w2v.x, a2[s]);
                    a2[s] = fmaf(h4.y, w2v.y, a2[s]);
                    a2[s] = fmaf(h4.z, w2v.z, a2[s]);
                    a2[s] = fmaf(h4.w, w2v.w, a2[s]);
                }
            }

            // gate update: thread j has r,z,n partials for h-dim j, 8 samples
            const float* xr0 = xb + (size_t)row * 768;
            #pragma unroll
            for (int s = 0; s < 8; s++) {
                const float* xr = xr0 + (size_t)s * 49152;   // 64*768 per sample
                const float xv0 = xr[0], xv1 = xr[256], xv2 = xr[512];
                const float rg = 1.f / (1.f + expf(-(xv0 + a0[s] + bh0)));
                const float zg = 1.f / (1.f + expf(-(xv1 + a1[s] + bh1)));
                const float ng = tanhf(xv2 + rg * (a2[s] + bh2));
                const float hv = h_cur[s * 256 + tid];
                float hn = (1.f - zg) * ng + zg * hv;
                if (p >= lenv[s]) hn = hv;     // hold state past sequence end
                h_nxt[s * 256 + tid] = hn;
                if (p < lenv[s])
                    Y[((size_t)((sg * 8 + s) * 512 + p)) * 512 + d * 256 + tid] = hn;
            }
            __syncthreads();
            float* t = h_cur; h_cur = h_nxt; h_nxt = t;
        }
        #pragma unroll
        for (int s = 0; s < 8; s++) hst[s * 256 + tid] = h_cur[s * 256 + tid];
    } else {
        // ================= GEMM role (unchanged) =================
        float (*As)[68]  = (float(*)[68])smem;
        float (*Bs)[132] = (float(*)[132])(smem + 544);

        const int gid  = blockIdx.x - NR;
        const int nt   = gid % 6;
        const int rest = gid / 6;
        const int d    = (rest >= Bg) ? 1 : 0;
        const int s    = rest - d * Bg;
        const int lo   = d ? (nch - 1 - r) * 64 : r * 64;
        if (lo < 0 || lo >= 512) return;
        if (lengths[perm[g0 + s]] <= lo) return;   // chunk fully masked

        float acc[4][8] = {};
        const int tm = tid >> 4;                 // rows tm*4..+3
        const int tn = tid & 15;                 // cols {tn*4..+3, 64+tn*4..+3}
        const int arr = tid >> 2, ak = (tid & 3) * 2;
        const int bn = tid >> 1, bk = (tid & 1) * 4;

        const float* Ap = A + (size_t)(s * 512 + lo + arr) * K + ak;
        const float* Wp = W + ((size_t)d * 768 + nt * 128 + bn) * K + bk;

        for (int k0 = 0; k0 < K; k0 += 8) {
            float2 av = *(const float2*)(Ap + k0);
            float4 bv = *(const float4*)(Wp + k0);
            __syncthreads();
            As[ak][arr] = av.x; As[ak + 1][arr] = av.y;
            Bs[bk + 0][bn] = bv.x; Bs[bk + 1][bn] = bv.y;
            Bs[bk + 2][bn] = bv.z; Bs[bk + 3][bn] = bv.w;
            __syncthreads();
            #pragma unroll
            for (int kk = 0; kk < 8; kk++) {
                float4 a4 = *(const float4*)&As[kk][tm * 4];
                float4 b0v = *(const float4*)&Bs[kk][tn * 4];
                float4 b1v = *(const float4*)&Bs[kk][64 + tn * 4];
                float ar4[4] = {a4.x, a4.y, a4.z, a4.w};
                float br[8] = {b0v.x, b0v.y, b0v.z, b0v.w,
                               b1v.x, b1v.y, b1v.z, b1v.w};
                #pragma unroll
                for (int i = 0; i < 4; i++)
                    #pragma unroll
                    for (int j = 0; j < 8; j++)
                        acc[i][j] = fmaf(ar4[i], br[j], acc[i][j]);
            }
        }
        const int cb = d * 768 + nt * 128;
        float bv0[4], bv1[4];
        #pragma unroll
        for (int j = 0; j < 4; j++) {
            bv0[j] = bi[cb + tn * 4 + j];
            bv1[j] = bi[cb + 64 + tn * 4 + j];
        }
        #pragma unroll
        for (int i = 0; i < 4; i++) {
            const int row = tm * 4 + i;
            float* o = xw_w + (size_t)((d * Bg + s) * 64 + row) * 768 + nt * 128 + tn * 4;
            float4 c0 = make_float4(acc[i][0] + bv0[0], acc[i][1] + bv0[1],
                                    acc[i][2] + bv0[2], acc[i][3] + bv0[3]);
            float4 c1 = make_float4(acc[i][4] + bv1[0], acc[i][5] + bv1[1],
                                    acc[i][6] + bv1[2], acc[i][7] + bv1[3]);
            *(float4*)(o)      = c0;
            *(float4*)(o + 64) = c1;
        }
    }
}

// ---------------- top-Q pooling + classifier head ----------------
__global__ __launch_bounds__(256)
void pool_k(const float* __restrict__ H, const int* __restrict__ lengths,
            const int* __restrict__ perm,
            const float* __restrict__ Wc, const float* __restrict__ bcp,
            float* __restrict__ out, int g0)
{
    const int bl = blockIdx.x;
    const int b  = perm[g0 + bl];
    const int tid = threadIdx.x;
    __shared__ float sc[512];
    __shared__ int   sel[128];
    __shared__ int   nsel;
    __shared__ float red[256];
    const int len = lengths[b];
    const int k = max(1, (int)ceilf((float)len * 0.15f));   // jnp fp32 semantics
    if (tid == 0) nsel = 0;
    for (int t = tid; t < 512; t += 256) {
        float s;
        if (t < len) {
            const float* row = H + ((size_t)bl * 512 + t) * 512;
            float acc = 0.f;
            for (int j = 0; j < 512; j++) acc = fmaf(row[j], row[j], acc);
            s = sqrtf(acc);
        } else s = -1e9f;
        sc[t] = s;
    }
    __syncthreads();
    // stable top-k: include t iff (#strictly greater) + (#equal, smaller idx) < k
    for (int t = tid; t < 512; t += 256) {
        if (t < len) {
            const float s = sc[t];
            int cnt = 0;
            for (int u = 0; u < 512; u++) {
                float su = sc[u];
                cnt += (su > s || (su == s && u < t)) ? 1 : 0;
            }
            if (cnt < k) { int p = atomicAdd(&nsel, 1); sel[p] = t; }
        }
    }
    __syncthreads();
    const int ns = nsel;                       // == k
    float part = 0.f;
    for (int j = tid; j < 512; j += 256) {
        float acc = 0.f;
        for (int i = 0; i < ns; i++)
            acc += H[((size_t)bl * 512 + sel[i]) * 512 + j];
        part += (acc / (float)k) * Wc[j];
    }
    red[tid] = part;
    __syncthreads();
    for (int s2 = 128; s2 > 0; s2 >>= 1) {
        if (tid < s2) red[tid] += red[tid + s2];
        __syncthreads();
    }
    if (tid == 0) out[b] = red[0] + bcp[0];
}

// ---------------- host ----------------
static inline size_t alup(size_t x) { return (x + 255) & ~255ull; }

static size_t tier_bytes(int Bg)
{
    return 2 * alup((size_t)Bg * 512 * 512 * 4)        // H ping-pong
         + 2 * alup((size_t)Bg * 2 * 64 * 768 * 4)     // xw ping-pong
         + alup(1966080ull * 4)                        // packed Whh
         + alup((size_t)2 * Bg * 256 * 4)              // hstate [2][Bg][256]
         + alup(2048);                                 // perm + nch
}

extern "C" void kernel_launch(void* const* d_in, const int* in_sizes, int n_in,
                              void* d_out, int out_size, void* d_ws, size_t ws_size,
                              hipStream_t stream)
{
    const float* x    = (const float*)d_in[0];
    const int*   len  = (const int*)  d_in[1];
    const float* ln_g = (const float*)d_in[2];
    const float* ln_b = (const float*)d_in[3];
    const float* w1   = (const float*)d_in[4];
    const float* b1   = (const float*)d_in[5];
    const float* w2   = (const float*)d_in[6];
    const float* b2   = (const float*)d_in[7];
    const float* Wih0 = (const float*)d_in[8];
    const float* Whh0 = (const float*)d_in[9];
    const float* bih0 = (const float*)d_in[10];
    const float* bhh0 = (const float*)d_in[11];
    const float* Wih  = (const float*)d_in[12];
    const float* Whh  = (const float*)d_in[13];
    const float* bih  = (const float*)d_in[14];
    const float* bhh  = (const float*)d_in[15];
    const float* Wc   = (const float*)d_in[16];
    const float* bc   = (const float*)d_in[17];
    float* out = (float*)d_out;

    int Bg = 0;
    const int tiers[6] = {256, 128, 64, 32, 16, 8};
    for (int i = 0; i < 6; i++)
        if (ws_size >= tier_bytes(tiers[i])) { Bg = tiers[i]; break; }
    if (Bg == 0) return;

    char* ws = (char*)d_ws;
    size_t off = 0;
    auto alloc = [&](size_t bytes) { size_t o = off; off += alup(bytes); return o; };
    float* h0    = (float*)(ws + alloc((size_t)Bg * 512 * 512 * 4));
    float* h1    = (float*)(ws + alloc((size_t)Bg * 512 * 512 * 4));
    float* xwA   = (float*)(ws + alloc((size_t)Bg * 2 * 64 * 768 * 4));
    float* xwB   = (float*)(ws + alloc((size_t)Bg * 2 * 64 * 768 * 4));
    float* whhT  = (float*)(ws + alloc(1966080ull * 4));
    float* hst   = (float*)(ws + alloc((size_t)2 * Bg * 256 * 4));
    int*   perm  = (int*)  (ws + alloc(2048));
    int*   nchp  = perm + 256;
    float* xwbuf[2] = {xwA, xwB};

    sort_k<<<1, 256, 0, stream>>>(len, perm, nchp, Bg);
    prep_whhT_k<<<7680, 256, 0, stream>>>(Whh0, Whh, whhT);

    const int NR = Bg >> 2;                // recur blocks: 2 dirs x Bg/8 subgroups
    const int NG = 12 * Bg;                // gemm blocks (6 col tiles x 2 dirs x Bg)

    for (int g0 = 0; g0 < 256; g0 += Bg) {
        const int gidx = g0 / Bg;
        input_proj_k<<<Bg * 512, 128, 0, stream>>>(x, len, perm, ln_g, ln_b,
                                                   w1, b1, w2, b2, h0, g0);
        float* bin = h0;
        float* bout = h1;
        for (int l = 0; l < 5; l++) {
            const int K = (l == 0) ? 128 : 512;
            const float* Wl  = (l == 0) ? Wih0 : (Wih + (size_t)(l - 1) * 2 * 768 * 512);
            const float* bil = (l == 0) ? bih0 : (bih + (size_t)(l - 1) * 1536);
            const float* whl = whhT + (size_t)l * 393216;
            const float* bhl = (l == 0) ? bhh0 : (bhh + (size_t)(l - 1) * 1536);
            for (int r = 0; r <= 8; r++) {
                round_k<<<NR + NG, 256, 0, stream>>>(
                    bin, K, Wl, bil, len, perm, nchp, gidx, g0, Bg,
                    xwbuf[r & 1], xwbuf[(r & 1) ^ 1],
                    whl, bhl, bout, hst, NR, r);
            }
            float* tmp = bin; bin = bout; bout = tmp;
        }
        pool_k<<<Bg, 256, 0, stream>>>(bin, len, perm, Wc, bc, out, g0);
    }
}

// Round 6
// 101489.087 us; speedup vs baseline: 1.8376x; 1.8376x over previous
//
#include <hip/hip_runtime.h>
#include <math.h>

// B=256 T=512 DIN=25 P=128 HID=256 3H=768 L=5 Q=0.15 EPS=1e-5
// Full-fp32. R10 = R9's 8-samples-per-stream recur (math verified, absmax
// 1e-6) with the measured execution-shape defects fixed:
//  R9 counters: recur dispatches at VALUBusy 1-3%, Occupancy 0.5-1.7% --
//  32-64 blocks x 256 thr = 1 wave/SIMD, zero TLP, and unroll-8 wanted 24
//  in-flight float4 (96 VGPR dests) vs 64 allocated -> serialized loads,
//  exposed L2 latency, 10-50x step blowup.
// Fixes: (a) 512-thread recur blocks, thread = (j=tid>>1, spair=tid&1) x 4
//  samples -> 2 waves/SIMD, lane pairs share j so weight loads coalesce;
//  (b) unroll 2 (6 loads, 24 dest VGPRs in budget); (c) GEMM role reshaped
//  for 512 threads (same 64x128 tile, 4x4 accs). LDS 16KB -> overlap kept.
// Whh stream per block-step still 768KB shared by 8 samples (8x fewer
// total stream bytes than R4's per-sample blocks -- the only lever that
// beats R4's aggregate-L2 wall).

#define CH 64

// ---------------- stable sort + per-group chunk counts ----------------
__global__ __launch_bounds__(256)
void sort_k(const int* __restrict__ len, int* __restrict__ perm,
            int* __restrict__ nchp, int Bg)
{
    __shared__ int ll[256];
    __shared__ int lp[256];
    const int i = threadIdx.x;
    const int li = len[i];
    ll[i] = li;
    __syncthreads();
    int rk = 0;
    for (int j = 0; j < 256; j++) {
        int lj = ll[j];
        rk += (lj < li || (lj == li && j < i)) ? 1 : 0;
    }
    lp[rk] = i;
    __syncthreads();
    perm[i] = lp[i];
    const int ngrp = 256 / Bg;
    if (i < ngrp) {
        int mx = ll[lp[i * Bg + Bg - 1]];      // ascending -> last rank is max
        int nch = (mx + 63) >> 6;
        nchp[i] = nch < 1 ? 1 : (nch > 8 ? 8 : nch);
    }
}

// ---------------- Whh pack: wpk[u][k4][g][j][k'] (same as R9, verified) --
// u = l*2+d. Element (u,k4,g,j,k') = Whh_raw[u][g*256+j][k4*4+k'].
// Lane j reads float4 at (k4*3+g)*256+j -> lane-consecutive, coalesced.
__global__ __launch_bounds__(256)
void prep_whhT_k(const float* __restrict__ Whh0, const float* __restrict__ Whh,
                 float* __restrict__ out)
{
    int id = blockIdx.x * 256 + threadIdx.x;   // exactly 1,966,080 threads
    int kp = id & 3;  int rest = id >> 2;
    int j  = rest & 255; rest >>= 8;
    int g3 = rest % 3;   rest /= 3;
    int k4 = rest & 63;  rest >>= 6;           // rest = u = l*2+d
    int l = rest >> 1, d = rest & 1;
    int row = g3 * 256 + j;
    int col = k4 * 4 + kp;
    out[id] = (l == 0) ? Whh0[(size_t)(d * 768 + row) * 256 + col]
                       : Whh[(size_t)(((l - 1) * 2 + d) * 768 + row) * 256 + col];
}

// ---------------- input projection: LN -> FC(25->128) -> GELU -> FC(128->128) --
__global__ __launch_bounds__(128)
void input_proj_k(const float* __restrict__ x, const int* __restrict__ lengths,
                  const int* __restrict__ perm,
                  const float* __restrict__ lng, const float* __restrict__ lnb,
                  const float* __restrict__ w1, const float* __restrict__ b1v,
                  const float* __restrict__ w2, const float* __restrict__ b2v,
                  float* __restrict__ out, int g0)
{
    const int btl = blockIdx.x;                // group-local (sl*512 + t)
    const int sl  = btl >> 9;
    const int t   = btl & 511;
    const int b   = perm[g0 + sl];
    if (t >= lengths[b]) return;               // masked rows never read downstream
    const int tid = threadIdx.x;
    __shared__ float xs[25];
    __shared__ float xn[25];
    __shared__ float hs[128];
    if (tid < 25) xs[tid] = x[((size_t)b * 512 + t) * 25 + tid];
    __syncthreads();
    if (tid < 25) {
        float mu = 0.f;
        #pragma unroll
        for (int k = 0; k < 25; k++) mu += xs[k];
        mu *= (1.f / 25.f);
        float var = 0.f;
        #pragma unroll
        for (int k = 0; k < 25; k++) { float dd = xs[k] - mu; var += dd * dd; }
        var *= (1.f / 25.f);
        float rstd = 1.f / sqrtf(var + 1e-5f);
        xn[tid] = (xs[tid] - mu) * rstd * lng[tid] + lnb[tid];
    }
    __syncthreads();
    float a = b1v[tid];
    #pragma unroll
    for (int k = 0; k < 25; k++) a = fmaf(xn[k], w1[k * 128 + tid], a);
    float ge = 0.5f * a * (1.f + erff(a * 0.70710678118654752440f));
    hs[tid] = ge;
    __syncthreads();
    float o = b2v[tid];
    #pragma unroll 8
    for (int k = 0; k < 128; k++) o = fmaf(hs[k], w2[k * 128 + tid], o);
    out[(size_t)btl * 128 + tid] = o;
}

// ---------------- fused round (512 threads) ----------------
// blocks [0, NR): recur role, NR = Bg/4. Block = (dir d, octet sg of 8
//   consecutive sorted samples). Thread (j=tid>>1, spair=tid&1) owns gates
//   {r,z,n} of h-dim j for samples {spair, spair+2, spair+4, spair+6}.
//   8 waves = 2/SIMD; weight loads: lane pairs share j -> 512B segments;
//   768KB/step L2 stream shared by 8 samples; h in 16KB LDS ping-pong;
//   1 barrier/step; NO cross-block traffic.
// blocks [NR, NR+12*Bg): GEMM role, 64Mx128N tile, 4x4 accs/thread.
__global__ __launch_bounds__(512)
void round_k(const float* __restrict__ A, int K,
             const float* __restrict__ W,      // raw Wih layer slice [2][768][K]
             const float* __restrict__ bi,     // [2][768]
             const int* __restrict__ lengths, const int* __restrict__ perm,
             const int* __restrict__ nchp, int gidx, int g0, int Bg,
             float* __restrict__ xw_w,         // gemm out (round r)
             const float* __restrict__ xw_r,   // recur in (round r-1)
             const float* __restrict__ whhT,   // packed layer slice (393216 f)
             const float* __restrict__ bhh,    // [2][768]
             float* __restrict__ Y,            // bout [Bg*512][512]
             float* __restrict__ hstate,       // [2][Bg][256]
             int NR, int r)
{
    __shared__ float smem[4096];               // 16KB union of both roles

    const int tid = threadIdx.x;
    const int nch = nchp[gidx];

    if ((int)blockIdx.x < NR) {
        // ================= recur role =================
        if (r == 0) return;
        const int half = NR >> 1;              // Bg/8 octets per dir
        const int d  = ((int)blockIdx.x >= half) ? 1 : 0;
        const int sg = (int)blockIdx.x - d * half;
        const int lo = d ? (nch - r) * CH : (r - 1) * CH;
        if (lo < 0 || lo >= 512) return;
        const int mlsg = lengths[perm[g0 + sg * 8 + 7]];   // octet max (sorted)
        int nst = min(lo + CH, mlsg) - lo;
        if (nst <= 0) return;
        const bool first = d ? (mlsg <= lo + CH) : (r == 1);

        float* h_cur = smem;                   // [8][256]
        float* h_nxt = smem + 2048;

        const int j     = tid >> 1;            // h-dim 0..255
        const int spair = tid & 1;             // sample parity

        int lenv[4];
        #pragma unroll
        for (int si = 0; si < 4; si++)
            lenv[si] = lengths[perm[g0 + sg * 8 + spair + 2 * si]];

        const float bh0 = bhh[d * 768 + j];
        const float bh1 = bhh[d * 768 + 256 + j];
        const float bh2 = bhh[d * 768 + 512 + j];

        float* hst = hstate + (size_t)(d * Bg + sg * 8) * 256;
        if (first) {
            #pragma unroll
            for (int si = 0; si < 4; si++)
                h_cur[(spair + 2 * si) * 256 + j] = 0.f;
        } else {
            #pragma unroll
            for (int si = 0; si < 4; si++) {
                const int s = spair + 2 * si;
                h_cur[s * 256 + j] = hst[s * 256 + j];
            }
        }
        __syncthreads();

        // packed weights: lane pairs share j -> coalesced 512B segments
        const float4* wd4 = (const float4*)whhT + (size_t)d * 49152 + j;
        const float* xb = xw_r + ((size_t)(d * Bg + sg * 8) * 64) * 768 + j;

        for (int st = 0; st < nst; st++) {
            const int p   = d ? (lo + nst - 1 - st) : (lo + st);
            const int row = p - lo;

            // xw prefetch (independent of h; hides under phase1)
            float xv0[4], xv1[4], xv2[4];
            #pragma unroll
            for (int si = 0; si < 4; si++) {
                const float* xr = xb + (size_t)(spair + 2 * si) * 49152
                                + (size_t)row * 768;
                xv0[si] = xr[0]; xv1[si] = xr[256]; xv2[si] = xr[512];
            }

            float a0[4], a1[4], a2[4];
            #pragma unroll
            for (int si = 0; si < 4; si++) { a0[si] = 0.f; a1[si] = 0.f; a2[si] = 0.f; }

            #pragma unroll 2
            for (int k4 = 0; k4 < 64; k4++) {
                const float4 w0v = wd4[(k4 * 3 + 0) * 256];
                const float4 w1v = wd4[(k4 * 3 + 1) * 256];
                const float4 w2v = wd4[(k4 * 3 + 2) * 256];
                #pragma unroll
                for (int si = 0; si < 4; si++) {
                    const float4 h4 = *(const float4*)
                        &h_cur[(spair + 2 * si) * 256 + k4 * 4];
                    a0[si] = fmaf(h4.x, w0v.x, a0[si]);
                    a0[si] = fmaf(h4.y, w0v.y, a0[si]);
                    a0[si] = fmaf(h4.z, w0v.z, a0[si]);
                    a0[si] = fmaf(h4.w, w0v.w, a0[si]);
                    a1[si] = fmaf(h4.x, w1v.x, a1[si]);
                    a1[si] = fmaf(h4.y, w1v.y, a1[si]);
                    a1[si] = fmaf(h4.z, w1v.z, a1[si]);
                    a1[si] = fmaf(h4.w, w1v.w, a1[si]);
                    a2[si] = fmaf(h4.x, w2v.x, a2[si]);
                    a2[si] = fmaf(h4.y, w2v.y, a2[si]);
                    a2[si] = fmaf(h4.z, w2v.z, a2[si]);
                    a2[si] = fmaf(h4.w, w2v.w, a2[si]);
                }
            }

            // gate update: thread has r,z,n partials for (j, its 4 samples)
            #pragma unroll
            for (int si = 0; si < 4; si++) {
                const int s = spair + 2 * si;
                const float rg = 1.f / (1.f + expf(-(xv0[si] + a0[si] + bh0)));
                const float zg = 1.f / (1.f + expf(-(xv1[si] + a1[si] + bh1)));
                const float ng = tanhf(xv2[si] + rg * (a2[si] + bh2));
                const float hv = h_cur[s * 256 + j];
                float hn = (1.f - zg) * ng + zg * hv;
                if (p >= lenv[si]) hn = hv;    // hold state past sequence end
                h_nxt[s * 256 + j] = hn;
                if (p < lenv[si])
                    Y[((size_t)((sg * 8 + s) * 512 + p)) * 512 + d * 256 + j] = hn;
            }
            __syncthreads();
            float* t = h_cur; h_cur = h_nxt; h_nxt = t;
        }
        #pragma unroll
        for (int si = 0; si < 4; si++) {
            const int s = spair + 2 * si;
            hst[s * 256 + j] = h_cur[s * 256 + j];
        }
    } else {
        // ================= GEMM role (512-thread reshape) =================
        float (*As)[68]  = (float(*)[68])smem;
        float (*Bs)[132] = (float(*)[132])(smem + 544);

        const int gid  = blockIdx.x - NR;
        const int nt   = gid % 6;
        const int rest = gid / 6;
        const int d    = (rest >= Bg) ? 1 : 0;
        const int s    = rest - d * Bg;
        const int lo   = d ? (nch - 1 - r) * 64 : r * 64;
        if (lo < 0 || lo >= 512) return;
        if (lengths[perm[g0 + s]] <= lo) return;   // chunk fully masked

        float acc[4][4] = {};
        const int am  = tid & 63;                // A row within tile
        const int ak8 = tid >> 6;                // A k 0..7
        const int bn  = tid >> 2;                // B col 0..127
        const int bk  = (tid & 3) * 2;           // B k {0,2,4,6}
        const int tm  = tid >> 5;                // out rows tm*4..+3 (0..15)
        const int tn  = tid & 31;                // out cols tn*4..+3 (0..31)

        const float* Ap = A + (size_t)(s * 512 + lo + am) * K + ak8;
        const float* Wp = W + ((size_t)d * 768 + nt * 128 + bn) * K + bk;

        for (int k0 = 0; k0 < K; k0 += 8) {
            float  av = Ap[k0];
            float2 bv = *(const float2*)(Wp + k0);
            __syncthreads();
            As[ak8][am] = av;
            Bs[bk][bn] = bv.x; Bs[bk + 1][bn] = bv.y;
            __syncthreads();
            #pragma unroll
            for (int kk = 0; kk < 8; kk++) {
                float4 a4 = *(const float4*)&As[kk][tm * 4];
                float4 b4 = *(const float4*)&Bs[kk][tn * 4];
                float ar[4] = {a4.x, a4.y, a4.z, a4.w};
                float br[4] = {b4.x, b4.y, b4.z, b4.w};
                #pragma unroll
                for (int i = 0; i < 4; i++)
                    #pragma unroll
                    for (int jj = 0; jj < 4; jj++)
                        acc[i][jj] = fmaf(ar[i], br[jj], acc[i][jj]);
            }
        }
        const int cb = d * 768 + nt * 128;
        float bv4[4];
        #pragma unroll
        for (int jj = 0; jj < 4; jj++) bv4[jj] = bi[cb + tn * 4 + jj];
        #pragma unroll
        for (int i = 0; i < 4; i++) {
            const int row = tm * 4 + i;
            float* o = xw_w + (size_t)((d * Bg + s) * 64 + row) * 768
                     + nt * 128 + tn * 4;
            float4 c = make_float4(acc[i][0] + bv4[0], acc[i][1] + bv4[1],
                                   acc[i][2] + bv4[2], acc[i][3] + bv4[3]);
            *(float4*)o = c;
        }
    }
}

// ---------------- top-Q pooling + classifier head ----------------
__global__ __launch_bounds__(256)
void pool_k(const float* __restrict__ H, const int* __restrict__ lengths,
            const int* __restrict__ perm,
            const float* __restrict__ Wc, const float* __restrict__ bcp,
            float* __restrict__ out, int g0)
{
    const int bl = blockIdx.x;
    const int b  = perm[g0 + bl];
    const int tid = threadIdx.x;
    __shared__ float sc[512];
    __shared__ int   sel[128];
    __shared__ int   nsel;
    __shared__ float red[256];
    const int len = lengths[b];
    const int k = max(1, (int)ceilf((float)len * 0.15f));   // jnp fp32 semantics
    if (tid == 0) nsel = 0;
    for (int t = tid; t < 512; t += 256) {
        float s;
        if (t < len) {
            const float* row = H + ((size_t)bl * 512 + t) * 512;
            float acc = 0.f;
            for (int j = 0; j < 512; j++) acc = fmaf(row[j], row[j], acc);
            s = sqrtf(acc);
        } else s = -1e9f;
        sc[t] = s;
    }
    __syncthreads();
    // stable top-k: include t iff (#strictly greater) + (#equal, smaller idx) < k
    for (int t = tid; t < 512; t += 256) {
        if (t < len) {
            const float s = sc[t];
            int cnt = 0;
            for (int u = 0; u < 512; u++) {
                float su = sc[u];
                cnt += (su > s || (su == s && u < t)) ? 1 : 0;
            }
            if (cnt < k) { int p = atomicAdd(&nsel, 1); sel[p] = t; }
        }
    }
    __syncthreads();
    const int ns = nsel;                       // == k
    float part = 0.f;
    for (int j = tid; j < 512; j += 256) {
        float acc = 0.f;
        for (int i = 0; i < ns; i++)
            acc += H[((size_t)bl * 512 + sel[i]) * 512 + j];
        part += (acc / (float)k) * Wc[j];
    }
    red[tid] = part;
    __syncthreads();
    for (int s2 = 128; s2 > 0; s2 >>= 1) {
        if (tid < s2) red[tid] += red[tid + s2];
        __syncthreads();
    }
    if (tid == 0) out[b] = red[0] + bcp[0];
}

// ---------------- host ----------------
static inline size_t alup(size_t x) { return (x + 255) & ~255ull; }

static size_t tier_bytes(int Bg)
{
    return 2 * alup((size_t)Bg * 512 * 512 * 4)        // H ping-pong
         + 2 * alup((size_t)Bg * 2 * 64 * 768 * 4)     // xw ping-pong
         + alup(1966080ull * 4)                        // packed Whh
         + alup((size_t)2 * Bg * 256 * 4)              // hstate [2][Bg][256]
         + alup(2048);                                 // perm + nch
}

extern "C" void kernel_launch(void* const* d_in, const int* in_sizes, int n_in,
                              void* d_out, int out_size, void* d_ws, size_t ws_size,
                              hipStream_t stream)
{
    const float* x    = (const float*)d_in[0];
    const int*   len  = (const int*)  d_in[1];
    const float* ln_g = (const float*)d_in[2];
    const float* ln_b = (const float*)d_in[3];
    const float* w1   = (const float*)d_in[4];
    const float* b1   = (const float*)d_in[5];
    const float* w2   = (const float*)d_in[6];
    const float* b2   = (const float*)d_in[7];
    const float* Wih0 = (const float*)d_in[8];
    const float* Whh0 = (const float*)d_in[9];
    const float* bih0 = (const float*)d_in[10];
    const float* bhh0 = (const float*)d_in[11];
    const float* Wih  = (const float*)d_in[12];
    const float* Whh  = (const float*)d_in[13];
    const float* bih  = (const float*)d_in[14];
    const float* bhh  = (const float*)d_in[15];
    const float* Wc   = (const float*)d_in[16];
    const float* bc   = (const float*)d_in[17];
    float* out = (float*)d_out;

    int Bg = 0;
    const int tiers[6] = {256, 128, 64, 32, 16, 8};
    for (int i = 0; i < 6; i++)
        if (ws_size >= tier_bytes(tiers[i])) { Bg = tiers[i]; break; }
    if (Bg == 0) return;

    char* ws = (char*)d_ws;
    size_t off = 0;
    auto alloc = [&](size_t bytes) { size_t o = off; off += alup(bytes); return o; };
    float* h0    = (float*)(ws + alloc((size_t)Bg * 512 * 512 * 4));
    float* h1    = (float*)(ws + alloc((size_t)Bg * 512 * 512 * 4));
    float* xwA   = (float*)(ws + alloc((size_t)Bg * 2 * 64 * 768 * 4));
    float* xwB   = (float*)(ws + alloc((size_t)Bg * 2 * 64 * 768 * 4));
    float* whhT  = (float*)(ws + alloc(1966080ull * 4));
    float* hst   = (float*)(ws + alloc((size_t)2 * Bg * 256 * 4));
    int*   perm  = (int*)  (ws + alloc(2048));
    int*   nchp  = perm + 256;
    float* xwbuf[2] = {xwA, xwB};

    sort_k<<<1, 256, 0, stream>>>(len, perm, nchp, Bg);
    prep_whhT_k<<<7680, 256, 0, stream>>>(Whh0, Whh, whhT);

    const int NR = Bg >> 2;                // recur blocks: 2 dirs x Bg/8 octets
    const int NG = 12 * Bg;                // gemm blocks (6 col tiles x 2 dirs x Bg)

    for (int g0 = 0; g0 < 256; g0 += Bg) {
        const int gidx = g0 / Bg;
        input_proj_k<<<Bg * 512, 128, 0, stream>>>(x, len, perm, ln_g, ln_b,
                                                   w1, b1, w2, b2, h0, g0);
        float* bin = h0;
        float* bout = h1;
        for (int l = 0; l < 5; l++) {
            const int K = (l == 0) ? 128 : 512;
            const float* Wl  = (l == 0) ? Wih0 : (Wih + (size_t)(l - 1) * 2 * 768 * 512);
            const float* bil = (l == 0) ? bih0 : (bih + (size_t)(l - 1) * 1536);
            const float* whl = whhT + (size_t)l * 393216;
            const float* bhl = (l == 0) ? bhh0 : (bhh + (size_t)(l - 1) * 1536);
            for (int r = 0; r <= 8; r++) {
                round_k<<<NR + NG, 512, 0, stream>>>(
                    bin, K, Wl, bil, len, perm, nchp, gidx, g0, Bg,
                    xwbuf[r & 1], xwbuf[(r & 1) ^ 1],
                    whl, bhl, bout, hst, NR, r);
            }
            float* tmp = bin; bin = bout; bout = tmp;
        }
        pool_k<<<Bg, 256, 0, stream>>>(bin, len, perm, Wc, bc, out, g0);
    }
}

// Round 7
// 56708.844 us; speedup vs baseline: 3.2887x; 1.7897x over previous
//
#include <hip/hip_runtime.h>
#include <math.h>

// B=256 T=512 DIN=25 P=128 HID=256 3H=768 L=5 Q=0.15 EPS=1e-5
// Full-fp32. R11: return to R4's PROVEN fused structure (48ms: recur
// blocks first, kq-split float4 weight loads -- the only shape measured
// to approach the 5.7us/step per-CU L2-port floor) with two levers:
//  (a) each recur block serves a PAIR of sorted samples per weight load
//      (same 192 float4/thread/step stream, 2x FMA still hidden under the
//      port wall, aggregate L2 halved per active sample);
//  (b) Bg=256 tier -> ONE sample group -> 45 serial rounds instead of 90
//      (the recurrence's serial-path is the binding constraint; halving
//      round count is worth more than any per-step micro-opt). Falls back
//      to Bg=128 if workspace < ~750MB.
// Lessons encoded: R5-R8 cross-block h-exchange pays ~2us/step RTT (>=
// the stream it saves); R9/R10 few-block sharing idles 7/8 of the chip;
// the 20-50ms "monster dispatches" in rocprof appear in EVERY version
// including the 48ms baseline -> profiling artifact, ignore.
// Per-sample tail handling (hold h for p>=len, write Y only p<len) was
// verified in R9/R10 (absmax 1e-6).

#define CH 64

// ---------------- stable sort + per-group chunk counts ----------------
__global__ __launch_bounds__(256)
void sort_k(const int* __restrict__ len, int* __restrict__ perm,
            int* __restrict__ nchp, int Bg)
{
    __shared__ int ll[256];
    __shared__ int lp[256];
    const int i = threadIdx.x;
    const int li = len[i];
    ll[i] = li;
    __syncthreads();
    int rk = 0;
    for (int j = 0; j < 256; j++) {
        int lj = ll[j];
        rk += (lj < li || (lj == li && j < i)) ? 1 : 0;
    }
    lp[rk] = i;
    __syncthreads();
    perm[i] = lp[i];
    const int ngrp = 256 / Bg;
    if (i < ngrp) {
        int mx = ll[lp[i * Bg + Bg - 1]];      // ascending -> last rank is max
        int nch = (mx + 63) >> 6;
        nchp[i] = nch < 1 ? 1 : (nch > 8 ? 8 : nch);
    }
}

// ---------------- Whh transpose: whhT[l][d][k][c]  (R4 layout) ----------
__global__ __launch_bounds__(256)
void prep_whhT_k(const float* __restrict__ Whh0, const float* __restrict__ Whh,
                 float* __restrict__ out)
{
    int id = blockIdx.x * 256 + threadIdx.x;   // exactly 1,966,080 threads
    int u = id / 196608, rr = id % 196608;     // u = l*2+d
    int k = rr / 768, c = rr % 768;
    int l = u >> 1, d = u & 1;
    out[id] = (l == 0) ? Whh0[(size_t)(d * 768 + c) * 256 + k]
                       : Whh[(size_t)(((l - 1) * 2 + d) * 768 + c) * 256 + k];
}

// ---------------- input projection: LN -> FC(25->128) -> GELU -> FC(128->128) --
__global__ __launch_bounds__(128)
void input_proj_k(const float* __restrict__ x, const int* __restrict__ lengths,
                  const int* __restrict__ perm,
                  const float* __restrict__ lng, const float* __restrict__ lnb,
                  const float* __restrict__ w1, const float* __restrict__ b1v,
                  const float* __restrict__ w2, const float* __restrict__ b2v,
                  float* __restrict__ out, int g0)
{
    const int btl = blockIdx.x;                // group-local (sl*512 + t)
    const int sl  = btl >> 9;
    const int t   = btl & 511;
    const int b   = perm[g0 + sl];
    if (t >= lengths[b]) return;               // masked rows never read downstream
    const int tid = threadIdx.x;
    __shared__ float xs[25];
    __shared__ float xn[25];
    __shared__ float hs[128];
    if (tid < 25) xs[tid] = x[((size_t)b * 512 + t) * 25 + tid];
    __syncthreads();
    if (tid < 25) {
        float mu = 0.f;
        #pragma unroll
        for (int k = 0; k < 25; k++) mu += xs[k];
        mu *= (1.f / 25.f);
        float var = 0.f;
        #pragma unroll
        for (int k = 0; k < 25; k++) { float dd = xs[k] - mu; var += dd * dd; }
        var *= (1.f / 25.f);
        float rstd = 1.f / sqrtf(var + 1e-5f);
        xn[tid] = (xs[tid] - mu) * rstd * lng[tid] + lnb[tid];
    }
    __syncthreads();
    float a = b1v[tid];
    #pragma unroll
    for (int k = 0; k < 25; k++) a = fmaf(xn[k], w1[k * 128 + tid], a);
    float ge = 0.5f * a * (1.f + erff(a * 0.70710678118654752440f));
    hs[tid] = ge;
    __syncthreads();
    float o = b2v[tid];
    #pragma unroll 8
    for (int k = 0; k < 128; k++) o = fmaf(hs[k], w2[k * 128 + tid], o);
    out[(size_t)btl * 128 + tid] = o;
}

// ---------------- fused round: recur(chunk r-1) blocks FIRST, gemm(chunk r) --
// blocks [0, NR): recur role, NR = Bg. One (dir d, sample PAIR pg) per
//   block, 256 thr, K split in quarters (kq) with float4 weight loads
//   (R4's measured-best shape), each weight float4 reused for BOTH
//   samples. gs partial exchange, 2 syncs/step.
// blocks [NR, NR+12*Bg): GEMM role (R4 verbatim). 64Mx128N tile.
__global__ __launch_bounds__(256)
void round_k(const float* __restrict__ A, int K,
             const float* __restrict__ W,      // raw Wih layer slice [2][768][K]
             const float* __restrict__ bi,     // [2][768]
             const int* __restrict__ lengths, const int* __restrict__ perm,
             const int* __restrict__ nchp, int gidx, int g0, int Bg,
             float* __restrict__ xw_w,         // gemm out (round r)
             const float* __restrict__ xw_r,   // recur in (round r-1)
             const float* __restrict__ whhT,   // layer slice [2][256][768]
             const float* __restrict__ bhh,    // [2][768]
             float* __restrict__ Y,            // bout [Bg*512][512]
             float* __restrict__ hstate,       // [2*Bg][256]
             int NR, int r)
{
    __shared__ float smem[6728];               // 26912B union of both roles

    const int tid = threadIdx.x;
    const int nch = nchp[gidx];

    if ((int)blockIdx.x < NR) {
        // ================= recur role (sample pair) =================
        if (r == 0) return;
        const int half = NR >> 1;              // Bg/2 pairs per dir
        const int d  = ((int)blockIdx.x >= half) ? 1 : 0;
        const int pg = (int)blockIdx.x - d * half;
        const int s0 = pg * 2;                 // pair: s0, s0+1 (sorted)
        const int lo = d ? (nch - r) * CH : (r - 1) * CH;
        if (lo < 0 || lo >= 512) return;
        const int len0 = lengths[perm[g0 + s0]];
        const int len1 = lengths[perm[g0 + s0 + 1]];   // pair max (sorted)
        int nst = min(lo + CH, len1) - lo;
        if (nst <= 0) return;                  // chunk beyond pair entirely
        const bool first = d ? (len1 <= lo + CH) : (r == 1);

        float* h_s0 = smem;                    // [260]
        float* h_s1 = smem + 260;              // [260]
        float* gs   = smem + 520;              // [2][4][776]

        float* hg = hstate + (size_t)(d * Bg + s0) * 256;
        if (first) {
            h_s0[tid] = 0.f;
            h_s1[tid] = 0.f;
        } else {
            h_s0[tid] = hg[tid];
            h_s1[tid] = hg[256 + tid];
        }
        __syncthreads();

        const int kq  = tid >> 6;              // K quarter 0..3
        const int q4  = (tid & 63) * 4;        // col-4 base within gate
        const float* Wd  = whhT + (size_t)d * 196608;
        const float* xw0 = xw_r + (size_t)(d * Bg + s0) * 64 * 768;
        const float* xw1 = xw0 + 49152;        // next sample (64*768)
        const float bh0 = bhh[d * 768 + tid];
        const float bh1 = bhh[d * 768 + 256 + tid];
        const float bh2 = bhh[d * 768 + 512 + tid];

        for (int st = 0; st < nst; st++) {
            const int p   = d ? (lo + nst - 1 - st) : (lo + st);
            const int row = p - lo;
            // phase 1: partial gh over this thread's K quarter, 12 cols,
            // both samples sharing every weight load
            float a0a[4] = {}, a1a[4] = {}, a2a[4] = {};
            float a0b[4] = {}, a1b[4] = {}, a2b[4] = {};
            const float* wk = Wd + (size_t)(kq * 64) * 768 + q4;
            #pragma unroll 4
            for (int k4 = 0; k4 < 16; k4++) {
                float4 h4a = *(const float4*)&h_s0[kq * 64 + k4 * 4];
                float4 h4b = *(const float4*)&h_s1[kq * 64 + k4 * 4];
                const float* w0 = wk + (size_t)(k4 * 4) * 768;
                float ha[4] = {h4a.x, h4a.y, h4a.z, h4a.w};
                float hb[4] = {h4b.x, h4b.y, h4b.z, h4b.w};
                #pragma unroll
                for (int kk = 0; kk < 4; kk++) {
                    const float* wr = w0 + (size_t)kk * 768;
                    float4 wv0 = *(const float4*)(wr);
                    float4 wv1 = *(const float4*)(wr + 256);
                    float4 wv2 = *(const float4*)(wr + 512);
                    float hav = ha[kk], hbv = hb[kk];
                    a0a[0] = fmaf(hav, wv0.x, a0a[0]); a0a[1] = fmaf(hav, wv0.y, a0a[1]);
                    a0a[2] = fmaf(hav, wv0.z, a0a[2]); a0a[3] = fmaf(hav, wv0.w, a0a[3]);
                    a1a[0] = fmaf(hav, wv1.x, a1a[0]); a1a[1] = fmaf(hav, wv1.y, a1a[1]);
                    a1a[2] = fmaf(hav, wv1.z, a1a[2]); a1a[3] = fmaf(hav, wv1.w, a1a[3]);
                    a2a[0] = fmaf(hav, wv2.x, a2a[0]); a2a[1] = fmaf(hav, wv2.y, a2a[1]);
                    a2a[2] = fmaf(hav, wv2.z, a2a[2]); a2a[3] = fmaf(hav, wv2.w, a2a[3]);
                    a0b[0] = fmaf(hbv, wv0.x, a0b[0]); a0b[1] = fmaf(hbv, wv0.y, a0b[1]);
                    a0b[2] = fmaf(hbv, wv0.z, a0b[2]); a0b[3] = fmaf(hbv, wv0.w, a0b[3]);
                    a1b[0] = fmaf(hbv, wv1.x, a1b[0]); a1b[1] = fmaf(hbv, wv1.y, a1b[1]);
                    a1b[2] = fmaf(hbv, wv1.z, a1b[2]); a1b[3] = fmaf(hbv, wv1.w, a1b[3]);
                    a2b[0] = fmaf(hbv, wv2.x, a2b[0]); a2b[1] = fmaf(hbv, wv2.y, a2b[1]);
                    a2b[2] = fmaf(hbv, wv2.z, a2b[2]); a2b[3] = fmaf(hbv, wv2.w, a2b[3]);
                }
            }
            {
                float* g0p = gs + (size_t)kq * 776;
                float* g1p = gs + (size_t)(4 + kq) * 776;
                *(float4*)&g0p[q4]       = make_float4(a0a[0], a0a[1], a0a[2], a0a[3]);
                *(float4*)&g0p[256 + q4] = make_float4(a1a[0], a1a[1], a1a[2], a1a[3]);
                *(float4*)&g0p[512 + q4] = make_float4(a2a[0], a2a[1], a2a[2], a2a[3]);
                *(float4*)&g1p[q4]       = make_float4(a0b[0], a0b[1], a0b[2], a0b[3]);
                *(float4*)&g1p[256 + q4] = make_float4(a1b[0], a1b[1], a1b[2], a1b[3]);
                *(float4*)&g1p[512 + q4] = make_float4(a2b[0], a2b[1], a2b[2], a2b[3]);
            }
            __syncthreads();
            // phase 2: gate update for h-dim j = tid, both samples
            #pragma unroll
            for (int sp = 0; sp < 2; sp++) {
                const float* gp = gs + (size_t)(sp * 4) * 776;
                float gr = bh0 + gp[tid] + gp[776 + tid]
                               + gp[1552 + tid] + gp[2328 + tid];
                float gz = bh1 + gp[256 + tid] + gp[1032 + tid]
                               + gp[1808 + tid] + gp[2584 + tid];
                float gn = bh2 + gp[512 + tid] + gp[1288 + tid]
                               + gp[2064 + tid] + gp[2840 + tid];
                const float* xr = (sp ? xw1 : xw0) + (size_t)row * 768;
                float rg = 1.f / (1.f + expf(-(xr[tid] + gr)));
                float zg = 1.f / (1.f + expf(-(xr[256 + tid] + gz)));
                float ng = tanhf(xr[512 + tid] + rg * gn);
                float* hsp = sp ? h_s1 : h_s0;
                const int lensp = sp ? len1 : len0;
                float hv = hsp[tid];
                float hn = (1.f - zg) * ng + zg * hv;
                if (p >= lensp) hn = hv;       // hold state past sequence end
                hsp[tid] = hn;
                if (p < lensp)
                    Y[((size_t)((s0 + sp) * 512 + p)) * 512 + d * 256 + tid] = hn;
            }
            __syncthreads();
        }
        hg[tid]       = h_s0[tid];
        hg[256 + tid] = h_s1[tid];
    } else {
        // ================= GEMM role (R4 verbatim) =================
        float (*As)[68]  = (float(*)[68])smem;
        float (*Bs)[132] = (float(*)[132])(smem + 544);

        const int gid  = blockIdx.x - NR;
        const int nt   = gid % 6;
        const int rest = gid / 6;
        const int d    = (rest >= Bg) ? 1 : 0;
        const int s    = rest - d * Bg;
        const int lo   = d ? (nch - 1 - r) * 64 : r * 64;
        if (lo < 0 || lo >= 512) return;
        if (lengths[perm[g0 + s]] <= lo) return;   // chunk fully masked

        float acc[4][8] = {};
        const int tm = tid >> 4;                 // rows tm*4..+3
        const int tn = tid & 15;                 // cols {tn*4..+3, 64+tn*4..+3}
        const int arr = tid >> 2, ak = (tid & 3) * 2;
        const int bn = tid >> 1, bk = (tid & 1) * 4;

        const float* Ap = A + (size_t)(s * 512 + lo + arr) * K + ak;
        const float* Wp = W + ((size_t)d * 768 + nt * 128 + bn) * K + bk;

        for (int k0 = 0; k0 < K; k0 += 8) {
            float2 av = *(const float2*)(Ap + k0);
            float4 bv = *(const float4*)(Wp + k0);
            __syncthreads();
            As[ak][arr] = av.x; As[ak + 1][arr] = av.y;
            Bs[bk + 0][bn] = bv.x; Bs[bk + 1][bn] = bv.y;
            Bs[bk + 2][bn] = bv.z; Bs[bk + 3][bn] = bv.w;
            __syncthreads();
            #pragma unroll
            for (int kk = 0; kk < 8; kk++) {
                float4 a4 = *(const float4*)&As[kk][tm * 4];
                float4 b0v = *(const float4*)&Bs[kk][tn * 4];
                float4 b1v = *(const float4*)&Bs[kk][64 + tn * 4];
                float ar4[4] = {a4.x, a4.y, a4.z, a4.w};
                float br[8] = {b0v.x, b0v.y, b0v.z, b0v.w,
                               b1v.x, b1v.y, b1v.z, b1v.w};
                #pragma unroll
                for (int i = 0; i < 4; i++)
                    #pragma unroll
                    for (int j = 0; j < 8; j++)
                        acc[i][j] = fmaf(ar4[i], br[j], acc[i][j]);
            }
        }
        const int cb = d * 768 + nt * 128;
        float bv0[4], bv1[4];
        #pragma unroll
        for (int j = 0; j < 4; j++) {
            bv0[j] = bi[cb + tn * 4 + j];
            bv1[j] = bi[cb + 64 + tn * 4 + j];
        }
        #pragma unroll
        for (int i = 0; i < 4; i++) {
            const int row = tm * 4 + i;
            float* o = xw_w + (size_t)((d * Bg + s) * 64 + row) * 768 + nt * 128 + tn * 4;
            float4 c0 = make_float4(acc[i][0] + bv0[0], acc[i][1] + bv0[1],
                                    acc[i][2] + bv0[2], acc[i][3] + bv0[3]);
            float4 c1 = make_float4(acc[i][4] + bv1[0], acc[i][5] + bv1[1],
                                    acc[i][6] + bv1[2], acc[i][7] + bv1[3]);
            *(float4*)(o)      = c0;
            *(float4*)(o + 64) = c1;
        }
    }
}

// ---------------- top-Q pooling + classifier head ----------------
__global__ __launch_bounds__(256)
void pool_k(const float* __restrict__ H, const int* __restrict__ lengths,
            const int* __restrict__ perm,
            const float* __restrict__ Wc, const float* __restrict__ bcp,
            float* __restrict__ out, int g0)
{
    const int bl = blockIdx.x;
    const int b  = perm[g0 + bl];
    const int tid = threadIdx.x;
    __shared__ float sc[512];
    __shared__ int   sel[128];
    __shared__ int   nsel;
    __shared__ float red[256];
    const int len = lengths[b];
    const int k = max(1, (int)ceilf((float)len * 0.15f));   // jnp fp32 semantics
    if (tid == 0) nsel = 0;
    for (int t = tid; t < 512; t += 256) {
        float s;
        if (t < len) {
            const float* row = H + ((size_t)bl * 512 + t) * 512;
            float acc = 0.f;
            for (int j = 0; j < 512; j++) acc = fmaf(row[j], row[j], acc);
            s = sqrtf(acc);
        } else s = -1e9f;
        sc[t] = s;
    }
    __syncthreads();
    // stable top-k: include t iff (#strictly greater) + (#equal, smaller idx) < k
    for (int t = tid; t < 512; t += 256) {
        if (t < len) {
            const float s = sc[t];
            int cnt = 0;
            for (int u = 0; u < 512; u++) {
                float su = sc[u];
                cnt += (su > s || (su == s && u < t)) ? 1 : 0;
            }
            if (cnt < k) { int p = atomicAdd(&nsel, 1); sel[p] = t; }
        }
    }
    __syncthreads();
    const int ns = nsel;                       // == k
    float part = 0.f;
    for (int j = tid; j < 512; j += 256) {
        float acc = 0.f;
        for (int i = 0; i < ns; i++)
            acc += H[((size_t)bl * 512 + sel[i]) * 512 + j];
        part += (acc / (float)k) * Wc[j];
    }
    red[tid] = part;
    __syncthreads();
    for (int s2 = 128; s2 > 0; s2 >>= 1) {
        if (tid < s2) red[tid] += red[tid + s2];
        __syncthreads();
    }
    if (tid == 0) out[b] = red[0] + bcp[0];
}

// ---------------- host ----------------
static inline size_t alup(size_t x) { return (x + 255) & ~255ull; }

static size_t tier_bytes(int Bg)
{
    return 2 * alup((size_t)Bg * 512 * 512 * 4)        // H ping-pong
         + 2 * alup((size_t)Bg * 2 * 64 * 768 * 4)     // xw ping-pong
         + alup(1966080ull * 4)                        // whhT
         + alup((size_t)2 * Bg * 256 * 4)              // hstate
         + alup(2048);                                 // perm + nch
}

extern "C" void kernel_launch(void* const* d_in, const int* in_sizes, int n_in,
                              void* d_out, int out_size, void* d_ws, size_t ws_size,
                              hipStream_t stream)
{
    const float* x    = (const float*)d_in[0];
    const int*   len  = (const int*)  d_in[1];
    const float* ln_g = (const float*)d_in[2];
    const float* ln_b = (const float*)d_in[3];
    const float* w1   = (const float*)d_in[4];
    const float* b1   = (const float*)d_in[5];
    const float* w2   = (const float*)d_in[6];
    const float* b2   = (const float*)d_in[7];
    const float* Wih0 = (const float*)d_in[8];
    const float* Whh0 = (const float*)d_in[9];
    const float* bih0 = (const float*)d_in[10];
    const float* bhh0 = (const float*)d_in[11];
    const float* Wih  = (const float*)d_in[12];
    const float* Whh  = (const float*)d_in[13];
    const float* bih  = (const float*)d_in[14];
    const float* bhh  = (const float*)d_in[15];
    const float* Wc   = (const float*)d_in[16];
    const float* bc   = (const float*)d_in[17];
    float* out = (float*)d_out;

    int Bg = 0;
    const int tiers[6] = {256, 128, 64, 32, 16, 8};
    for (int i = 0; i < 6; i++)
        if (ws_size >= tier_bytes(tiers[i])) { Bg = tiers[i]; break; }
    if (Bg == 0) return;

    char* ws = (char*)d_ws;
    size_t off = 0;
    auto alloc = [&](size_t bytes) { size_t o = off; off += alup(bytes); return o; };
    float* h0    = (float*)(ws + alloc((size_t)Bg * 512 * 512 * 4));
    float* h1    = (float*)(ws + alloc((size_t)Bg * 512 * 512 * 4));
    float* xwA   = (float*)(ws + alloc((size_t)Bg * 2 * 64 * 768 * 4));
    float* xwB   = (float*)(ws + alloc((size_t)Bg * 2 * 64 * 768 * 4));
    float* whhT  = (float*)(ws + alloc(1966080ull * 4));
    float* hst   = (float*)(ws + alloc((size_t)2 * Bg * 256 * 4));
    int*   perm  = (int*)  (ws + alloc(2048));
    int*   nchp  = perm + 256;
    float* xwbuf[2] = {xwA, xwB};

    sort_k<<<1, 256, 0, stream>>>(len, perm, nchp, Bg);
    prep_whhT_k<<<7680, 256, 0, stream>>>(Whh0, Whh, whhT);

    const int NR = Bg;                     // recur blocks: 2 dirs x Bg/2 pairs
    const int NG = 12 * Bg;                // gemm blocks (6 col tiles x 2 dirs x Bg)

    for (int g0 = 0; g0 < 256; g0 += Bg) {
        const int gidx = g0 / Bg;
        input_proj_k<<<Bg * 512, 128, 0, stream>>>(x, len, perm, ln_g, ln_b,
                                                   w1, b1, w2, b2, h0, g0);
        float* bin = h0;
        float* bout = h1;
        for (int l = 0; l < 5; l++) {
            const int K = (l == 0) ? 128 : 512;
            const float* Wl  = (l == 0) ? Wih0 : (Wih + (size_t)(l - 1) * 2 * 768 * 512);
            const float* bil = (l == 0) ? bih0 : (bih + (size_t)(l - 1) * 1536);
            const float* whl = whhT + (size_t)l * 393216;
            const float* bhl = (l == 0) ? bhh0 : (bhh + (size_t)(l - 1) * 1536);
            for (int r = 0; r <= 8; r++) {
                round_k<<<NR + NG, 256, 0, stream>>>(
                    bin, K, Wl, bil, len, perm, nchp, gidx, g0, Bg,
                    xwbuf[r & 1], xwbuf[(r & 1) ^ 1],
                    whl, bhl, bout, hst, NR, r);
            }
            float* tmp = bin; bin = bout; bout = tmp;
        }
        pool_k<<<Bg, 256, 0, stream>>>(bin, len, perm, Wc, bc, out, g0);
    }
}